// Round 1
// 566.649 us; speedup vs baseline: 1.2338x; 1.2338x over previous
//
#include <hip/hip_runtime.h>

namespace {
constexpr int kB = 256;
constexpr int kS = 2048;
constexpr int kV = 10;
constexpr int kE = 32;
constexpr int kH = 64;
constexpr int kO = 10;
constexpr int kT = 16;      // steps per tile
constexpr int kPad = 68;    // LDS row stride in floats (272 B, 16B-aligned)
constexpr int kTiles = kS / kT;   // 128
// Fold tanh's 2x and log2(e) into weights: s = kC*(xw + h.Wh + b), e^{2p} = 2^s
constexpr float kC = 2.885390081777927f;   // 2*log2(e)

__device__ __forceinline__ float step_tanh(float s) {
    s = __builtin_amdgcn_fmed3f(s, -26.f, 26.f);
    float e = __builtin_amdgcn_exp2f(s);
    float r = __builtin_amdgcn_rcpf(e + 1.f);
    return fmaf(-2.f, r, 1.f);              // tanh = 1 - 2/(e^{2p}+1)
}

// 16 recurrence steps with h carried in a REGISTER and broadcast via
// v_readlane -> SGPR. Critical path per step is now pure VALU:
//   h(VGPR) -> 64x readlane -> 64x fma (4 acc chains) -> tanh -> h
// No DS-pipe round trip (old version: 8x ds_read_b128 + ds_bpermute shfl per
// step, ~2x 120cy LDS latency on the serial chain). The history ds_write is
// write-only on the chain (consumed by wave 1 a tile later).
__device__ __forceinline__ float do_steps(float h, float* __restrict__ cur,
                                          const float* __restrict__ xw,
                                          const float* __restrict__ whc, int l)
{
    #pragma unroll
    for (int tl = 0; tl < kT; ++tl) {
        const int hb = __float_as_int(h);
        float a0 = xw[tl], a1 = 0.f, a2 = 0.f, a3 = 0.f;
        #pragma unroll
        for (int k = 0; k < kH; k += 4) {
            const float h0 = __int_as_float(__builtin_amdgcn_readlane(hb, k + 0));
            const float h1 = __int_as_float(__builtin_amdgcn_readlane(hb, k + 1));
            const float h2 = __int_as_float(__builtin_amdgcn_readlane(hb, k + 2));
            const float h3 = __int_as_float(__builtin_amdgcn_readlane(hb, k + 3));
            a0 = fmaf(h0, whc[k + 0], a0);   // SGPR x VGPR + VGPR: 1 sgpr read ok
            a1 = fmaf(h1, whc[k + 1], a1);
            a2 = fmaf(h2, whc[k + 2], a2);
            a3 = fmaf(h3, whc[k + 3], a3);
        }
        h = step_tanh((a0 + a1) + (a2 + a3));
        cur[tl * kPad + l] = h;   // history for logits wave (off critical path)
    }
    return h;
}

__device__ __forceinline__ void do_logits(const float* __restrict__ hb,
                                          const float (* __restrict__ WdT)[kPad],
                                          const float* __restrict__ bdL,
                                          float* __restrict__ out, int obase, int l)
{
    #pragma unroll
    for (int r = 0; r < 3; ++r) {
        int f = r * 64 + l;                  // flat (t_local, o), 160 total
        if (f < kT * kO) {
            int tl = f / kO;
            int o  = f - tl * kO;
            const float4* hb4 = reinterpret_cast<const float4*>(hb + tl * kPad);
            const float4* wd4 = reinterpret_cast<const float4*>(&WdT[o][0]);
            float a0 = bdL[o], a1 = 0.f, a2 = 0.f, a3 = 0.f;
            #pragma unroll
            for (int c = 0; c < kH / 4; ++c) {
                float4 h4 = hb4[c];
                float4 w4 = wd4[c];
                a0 = fmaf(h4.x, w4.x, a0);
                a1 = fmaf(h4.y, w4.y, a1);
                a2 = fmaf(h4.z, w4.z, a2);
                a3 = fmaf(h4.w, w4.w, a3);
            }
            out[obase + f] = (a0 + a1) + (a2 + a3);   // coalesced
        }
    }
}

// Wave 0: serial recurrence (latency-critical). Wave 1: logits for the
// previous tile out of the double-buffered h history. One barrier per tile;
// wave 1's per-tile work is ~1/3 of wave 0's, so wave 0 never stalls on it.
__global__ __launch_bounds__(128, 1)
void rnn_fused(const int* __restrict__ num1, const int* __restrict__ num2,
               const float* __restrict__ embed, const float* __restrict__ Wx,
               const float* __restrict__ Wh, const float* __restrict__ bias,
               const float* __restrict__ Wd, const float* __restrict__ bd,
               float* __restrict__ out)
{
    const int row = blockIdx.x;   // one sequence per block
    const int tid = threadIdx.x;
    const int w   = tid >> 6;     // 0 = recurrence wave, 1 = logits wave
    const int l   = tid & 63;     // lane owns hidden unit l (wave 0)

    __shared__ __align__(16) float TT[kV * kV][kH];     // kC*(xw+b), 100 rows
    __shared__ __align__(16) float hbuf[2][kT][kPad];   // double-buffered h history
    __shared__ __align__(16) float WdT[kO][kPad];
    __shared__ float bdL[kO];

    float whc[kH];                // wave 0: kC * Wh column l (full K)
    float xw[kT];
    float h = 0.f;
    int idx_next = 0;
    const int lane16 = l & 15;
    const int nb = row * kS;
    const int orow = row * (kS * kO);

    if (w == 0) {
        // ---- one-time setup: input-projection table + Wh column ----
        float wxc[2 * kE];
        #pragma unroll
        for (int k = 0; k < 2 * kE; ++k) wxc[k] = Wx[k * kH + l];  // Wx column l
        float bj = bias[l];
        float t1[kV], t2[kV];
        #pragma unroll
        for (int v = 0; v < kV; ++v) {
            float a0 = 0.f, a1 = 0.f;
            #pragma unroll
            for (int k = 0; k < kE; ++k) {
                float e = embed[v * kE + k];   // lane-uniform -> s_load
                a0 = fmaf(e, wxc[k], a0);
                a1 = fmaf(e, wxc[kE + k], a1);
            }
            t1[v] = a0; t2[v] = a1;
        }
        #pragma unroll
        for (int v1 = 0; v1 < kV; ++v1)
            #pragma unroll
            for (int v2 = 0; v2 < kV; ++v2)
                TT[v1 * kV + v2][l] = kC * (t1[v1] + t2[v2] + bj);
        #pragma unroll
        for (int k = 0; k < kH; ++k) whc[k] = kC * Wh[k * kH + l];
        idx_next = num1[nb + lane16] * kV + num2[nb + lane16];   // tile 0 idx
    } else {
        #pragma unroll
        for (int o = 0; o < kO; ++o) WdT[o][l] = Wd[l * kO + o];
        if (l < kO) bdL[l] = bd[l];
    }
    __syncthreads();

    for (int ti = 0; ti < kTiles; ++ti) {
        if (w == 0) {
            const int idxv = idx_next;
            if (ti + 1 < kTiles) {
                int tt = nb + (ti + 1) * kT + lane16;
                idx_next = num1[tt] * kV + num2[tt];   // prefetch next tile idx
            }
            #pragma unroll
            for (int tl = 0; tl < kT; ++tl) {
                int sidx = __builtin_amdgcn_readlane(idxv, tl);   // uniform
                xw[tl] = TT[sidx][l];
            }
            h = do_steps(h, &hbuf[ti & 1][0][0], xw, whc, l);
        } else if (ti > 0) {
            do_logits(&hbuf[(ti - 1) & 1][0][0], WdT, bdL, out,
                      orow + (ti - 1) * kT * kO, l);
        }
        __syncthreads();   // publish tile ti history / retire tile ti-1 reads
    }
    if (w == 1)
        do_logits(&hbuf[(kTiles - 1) & 1][0][0], WdT, bdL, out,
                  orow + (kS - kT) * kO, l);
}
} // namespace

extern "C" void kernel_launch(void* const* d_in, const int* in_sizes, int n_in,
                              void* d_out, int out_size, void* d_ws, size_t ws_size,
                              hipStream_t stream) {
    (void)in_sizes; (void)n_in; (void)d_ws; (void)ws_size; (void)out_size;
    rnn_fused<<<dim3(kB), dim3(128), 0, stream>>>(
        (const int*)d_in[0], (const int*)d_in[1],
        (const float*)d_in[2], (const float*)d_in[3],
        (const float*)d_in[4], (const float*)d_in[5],
        (const float*)d_in[6], (const float*)d_in[7],
        (float*)d_out);
}